// Round 1
// baseline (181.315 us; speedup 1.0000x reference)
//
#include <hip/hip_runtime.h>
#include <hip/hip_bf16.h>

typedef __attribute__((ext_vector_type(4))) float f32x4;
typedef __attribute__((ext_vector_type(8))) short bf16x8;

__device__ inline unsigned short f2b(float f) {
    union { float f; unsigned u; } v; v.f = f;
    unsigned r = v.u + 0x7FFF + ((v.u >> 16) & 1);  // RNE
    return (unsigned short)(r >> 16);
}
__device__ inline unsigned pack2(float lo, float hi) {
    return (unsigned)f2b(lo) | ((unsigned)f2b(hi) << 16);
}

#define LDB 40  // shorts per Bt row (80 B: 16B-aligned b128 reads, 2-way banks = free)

__global__ __launch_bounds__(256) void bmm2_kernel(const float* __restrict__ a,
                                                   const float* __restrict__ b,
                                                   float* __restrict__ out) {
    // Static ragged-batch tables (SEQLEN fixed in reference).
    const int  cumblk[9] = {0,64,192,448,640,736,896,1008,1088};
    const int  slen[8]   = {512,1024,2048,1536,768,1280,896,640};
    const long aoff[8]   = {0,4194304,20971520,88080384,125829120,135266304,161480704,174325760};
    const int  toff[8]   = {0,512,1536,3584,5120,5888,7168,8064};

    __shared__ unsigned short Bt[64 * LDB];  // B^T tile: [j=64][k=32(+pad)]

    int bid = blockIdx.x;
    int i = 0;
    #pragma unroll
    for (int t = 0; t < 7; ++t) if (bid >= cumblk[t + 1]) i = t + 1;

    int rem  = bid - cumblk[i];
    int s    = slen[i];
    int nmb  = s >> 7;             // 128-row blocks per head
    int head = rem / nmb;
    int mb   = rem - head * nmb;

    const float* A  = a + aoff[i] + (long)head * s * s + (long)mb * 128 * s;
    const float* Bp = b + (long)toff[i] * 1024 + head * 64;
    float*       Cp = out + (long)(toff[i] + mb * 128) * 1024 + head * 64;

    int tid  = threadIdx.x;
    int lane = tid & 63;
    int wave = tid >> 6;           // 4 waves: rows wave*32 .. wave*32+31 (2 M-tiles)
    int lrow = lane & 15;
    int lgrp = lane >> 4;          // k-group for MFMA fragments

    f32x4 acc[2][4] = {};          // [mtile][ntile] fp32 accumulators

    // B staging map: thread -> (k pair, 4 cols)
    int k2 = tid >> 4;             // 0..15 -> k = 2*k2
    int j0 = (tid & 15) * 4;

    const float* arow0 = A + (long)(wave * 32 + lrow) * s + lgrp * 8;
    const float* arow1 = arow0 + (long)16 * s;

    for (int k0 = 0; k0 < s; k0 += 32) {
        // ---- A: global -> VGPR fragments (no LDS; the 723 MB stream) ----
        f32x4 a00 = *(const f32x4*)(arow0 + k0);
        f32x4 a01 = *(const f32x4*)(arow0 + k0 + 4);
        f32x4 a10 = *(const f32x4*)(arow1 + k0);
        f32x4 a11 = *(const f32x4*)(arow1 + k0 + 4);

        // ---- B: global (coalesced rows) -> LDS transposed bf16 ----
        const float* bp = Bp + (long)(k0 + 2 * k2) * 1024 + j0;
        f32x4 b0 = *(const f32x4*)bp;
        f32x4 b1 = *(const f32x4*)(bp + 1024);

        __syncthreads();  // previous iter's Bt reads complete
        #pragma unroll
        for (int e = 0; e < 4; ++e)
            *(unsigned*)&Bt[(j0 + e) * LDB + 2 * k2] = pack2(b0[e], b1[e]);
        __syncthreads();

        // ---- B fragments from LDS (shared by both M-tiles) ----
        bf16x8 bf[4];
        #pragma unroll
        for (int nt = 0; nt < 4; ++nt)
            bf[nt] = *(const bf16x8*)&Bt[(nt * 16 + lrow) * LDB + lgrp * 8];

        // ---- convert A fp32 -> bf16 fragments ----
        bf16x8 af0, af1;
        #pragma unroll
        for (int e = 0; e < 4; ++e) {
            af0[e]     = (short)f2b(a00[e]);
            af0[e + 4] = (short)f2b(a01[e]);
            af1[e]     = (short)f2b(a10[e]);
            af1[e + 4] = (short)f2b(a11[e]);
        }

        #pragma unroll
        for (int nt = 0; nt < 4; ++nt) {
            acc[0][nt] = __builtin_amdgcn_mfma_f32_16x16x32_bf16(af0, bf[nt], acc[0][nt], 0, 0, 0);
            acc[1][nt] = __builtin_amdgcn_mfma_f32_16x16x32_bf16(af1, bf[nt], acc[1][nt], 0, 0, 0);
        }
    }

    // ---- epilogue: C/D layout col=lane&15, row=4*(lane>>4)+reg ----
    #pragma unroll
    for (int mt = 0; mt < 2; ++mt)
        #pragma unroll
        for (int nt = 0; nt < 4; ++nt)
            #pragma unroll
            for (int r = 0; r < 4; ++r) {
                int q = wave * 32 + mt * 16 + lgrp * 4 + r;
                Cp[(long)q * 1024 + nt * 16 + lrow] = acc[mt][nt][r];
            }
}

extern "C" void kernel_launch(void* const* d_in, const int* in_sizes, int n_in,
                              void* d_out, int out_size, void* d_ws, size_t ws_size,
                              hipStream_t stream) {
    const float* a = (const float*)d_in[0];
    const float* b = (const float*)d_in[1];
    float* out = (float*)d_out;
    bmm2_kernel<<<1088, 256, 0, stream>>>(a, b, out);
}